// Round 1
// baseline (687.828 us; speedup 1.0000x reference)
//
#include <hip/hip_runtime.h>

#define N_PATCH 1024
#define DIM     768
#define NH      12
#define HD      64
#define NB      4
#define TQ      2304   // 3*DIM
#define EPS     1e-6f

// ---------------------------------------------------------------------------
// Generic fp32 tiled GEMM: C[M,N] = A[M,K] @ B[K,N] (+ bias). 64x64 tile,
// BK=16, 256 threads, 4x4 micro-tile per thread. Pad LDS rows to 68 floats so
// compute reads are aligned float4 (b128) with <=2-way bank aliasing.
// ---------------------------------------------------------------------------
template <bool BIAS>
__global__ __launch_bounds__(256) void gemm_f32(
    const float* __restrict__ A, const float* __restrict__ Bm,
    const float* __restrict__ bias, float* __restrict__ C,
    int M, int K, int N)
{
    __shared__ float As[16][68];   // As[k][m]
    __shared__ float Bs[16][68];   // Bs[k][n]
    const int tid = threadIdx.x;
    const int tx = tid & 15, ty = tid >> 4;
    const int m0 = blockIdx.y * 64;
    const int n0 = blockIdx.x * 64;

    float acc[4][4] = {};

    for (int k0 = 0; k0 < K; k0 += 16) {
        // A tile 64x16 -> As[k][m] (transposed store, scalar writes, 2-way ok)
        {
            int row = tid >> 2;            // 0..63 (m)
            int kc  = (tid & 3) * 4;       // 0,4,8,12
            float4 a = *(const float4*)(A + (size_t)(m0 + row) * K + k0 + kc);
            As[kc + 0][row] = a.x; As[kc + 1][row] = a.y;
            As[kc + 2][row] = a.z; As[kc + 3][row] = a.w;
        }
        // B tile 16x64 -> Bs[k][n]
        {
            int row = tid >> 4;            // 0..15 (k)
            int nc  = (tid & 15) * 4;
            float4 b = *(const float4*)(Bm + (size_t)(k0 + row) * N + n0 + nc);
            *(float4*)&Bs[row][nc] = b;
        }
        __syncthreads();
        #pragma unroll
        for (int kk = 0; kk < 16; ++kk) {
            alignas(16) float a[4], b[4];
            *(float4*)a = *(const float4*)&As[kk][ty * 4];
            *(float4*)b = *(const float4*)&Bs[kk][tx * 4];
            #pragma unroll
            for (int i = 0; i < 4; ++i)
                #pragma unroll
                for (int j = 0; j < 4; ++j)
                    acc[i][j] += a[i] * b[j];
        }
        __syncthreads();
    }

    #pragma unroll
    for (int i = 0; i < 4; ++i) {
        int m = m0 + ty * 4 + i;
        int n = n0 + tx * 4;
        float4 o;
        o.x = acc[i][0]; o.y = acc[i][1]; o.z = acc[i][2]; o.w = acc[i][3];
        if (BIAS) {
            o.x += bias[n + 0]; o.y += bias[n + 1];
            o.z += bias[n + 2]; o.w += bias[n + 3];
        }
        *(float4*)(C + (size_t)m * N + n) = o;
    }
}

// ---------------------------------------------------------------------------
// Graph mix: for which in {0:q, 1:k}, bh in [0,48), m-tile of 64:
//   out[m,d] = f(m,d) + 0.1 * sum_n mask[n,m] * f(n,d),  f = relu(.)+EPS
// reading q/k straight out of the qkv buffer (layout [B,N,3C]).
// Result layout qk2[(which*48+bh)*1024 + m][d] (row-contiguous per head).
// ---------------------------------------------------------------------------
__global__ __launch_bounds__(256) void graphmix_kernel(
    const float* __restrict__ qkv, const float* __restrict__ mask,
    float* __restrict__ qk2)
{
    const int which = blockIdx.z;          // 0=q, 1=k
    const int bh = blockIdx.y;             // 0..47
    const int b = bh / NH, h = bh % NH;
    const int m0 = blockIdx.x * 64;

    __shared__ float Ms[16][68];   // Ms[n][m] = mask[n0+n][m0+m]
    __shared__ float Fs[16][68];   // Fs[n][d] = relu(q[n,d])+EPS

    const int tid = threadIdx.x;
    const int tx = tid & 15, ty = tid >> 4;
    const size_t qbase = (size_t)b * N_PATCH * TQ + (size_t)which * DIM + (size_t)h * HD;

    float acc[4][4] = {};   // [m_i][d_j]

    for (int n0 = 0; n0 < N_PATCH; n0 += 16) {
        const int row = tid >> 4;          // 0..15 (n local)
        const int c4  = (tid & 15) * 4;
        float4 mv = *(const float4*)(mask + (size_t)(n0 + row) * N_PATCH + m0 + c4);
        *(float4*)&Ms[row][c4] = mv;
        float4 qv = *(const float4*)(qkv + qbase + (size_t)(n0 + row) * TQ + c4);
        qv.x = fmaxf(qv.x, 0.f) + EPS; qv.y = fmaxf(qv.y, 0.f) + EPS;
        qv.z = fmaxf(qv.z, 0.f) + EPS; qv.w = fmaxf(qv.w, 0.f) + EPS;
        *(float4*)&Fs[row][c4] = qv;
        __syncthreads();
        #pragma unroll
        for (int kk = 0; kk < 16; ++kk) {
            alignas(16) float a[4], f[4];
            *(float4*)a = *(const float4*)&Ms[kk][ty * 4];
            *(float4*)f = *(const float4*)&Fs[kk][tx * 4];
            #pragma unroll
            for (int i = 0; i < 4; ++i)
                #pragma unroll
                for (int j = 0; j < 4; ++j)
                    acc[i][j] += a[i] * f[j];
        }
        __syncthreads();
    }

    float* ob = qk2 + (size_t)(which * 48 + bh) * N_PATCH * HD;
    #pragma unroll
    for (int i = 0; i < 4; ++i) {
        int m = m0 + ty * 4 + i;
        float4 qv = *(const float4*)(qkv + qbase + (size_t)m * TQ + tx * 4);
        float4 o;
        o.x = fmaxf(qv.x, 0.f) + EPS + 0.1f * acc[i][0];
        o.y = fmaxf(qv.y, 0.f) + EPS + 0.1f * acc[i][1];
        o.z = fmaxf(qv.z, 0.f) + EPS + 0.1f * acc[i][2];
        o.w = fmaxf(qv.w, 0.f) + EPS + 0.1f * acc[i][3];
        *(float4*)(ob + (size_t)m * HD + tx * 4) = o;
    }
}

// ---------------------------------------------------------------------------
// Attention: per (bh, n-tile of 64): loop m-tiles:
//   S = (Q'' K''^T) * mask ;  rowacc += rowsum(S) ;  O += S @ V
// epilogue: attn[b,n,h*64+d] = O[n,d] / (rowacc[n]+EPS)   ([B,N,C] layout)
// K tile stored transposed in LDS; S reuses the K buffer.
// ---------------------------------------------------------------------------
__global__ __launch_bounds__(256) void attn_kernel(
    const float* __restrict__ qk2, const float* __restrict__ qkv,
    const float* __restrict__ mask, float* __restrict__ attn)
{
    const int bh = blockIdx.y;
    const int b = bh / NH, h = bh % NH;
    const int n0 = blockIdx.x * 64;

    __shared__ float Qs[64][68];   // [n][d]
    __shared__ float KT[64][68];   // [d][m] for S-compute, then S[n][m]
    __shared__ float Vs[64][68];   // [m][d]
    __shared__ float rowacc[64];

    const int tid = threadIdx.x;
    const int tx = tid & 15, ty = tid >> 4;

    {   // Q tile
        const float* qb = qk2 + ((size_t)bh * N_PATCH + n0) * HD;
        #pragma unroll
        for (int r = 0; r < 4; ++r) {
            int row = r * 16 + (tid >> 4);
            int dc  = (tid & 15) * 4;
            *(float4*)&Qs[row][dc] = *(const float4*)(qb + (size_t)row * HD + dc);
        }
    }
    if (tid < 64) rowacc[tid] = 0.f;

    float oacc[4][4] = {};   // [n_i][d_j]

    for (int mt = 0; mt < 16; ++mt) {
        const int m0 = mt * 64;
        __syncthreads();   // previous iter's S/V consumers done
        {
            const float* kb = qk2 + ((size_t)(48 + bh) * N_PATCH + m0) * HD;
            const float* vb = qkv + ((size_t)b * N_PATCH + m0) * TQ + 2 * DIM + (size_t)h * HD;
            #pragma unroll
            for (int r = 0; r < 4; ++r) {
                int row = r * 16 + (tid >> 4);   // m local
                int dc  = (tid & 15) * 4;
                float4 kq = *(const float4*)(kb + (size_t)row * HD + dc);
                KT[dc + 0][row] = kq.x; KT[dc + 1][row] = kq.y;
                KT[dc + 2][row] = kq.z; KT[dc + 3][row] = kq.w;
                *(float4*)&Vs[row][dc] = *(const float4*)(vb + (size_t)row * TQ + dc);
            }
        }
        __syncthreads();

        // S = Q @ K^T  (4n x 4m per thread)
        float s[4][4] = {};
        #pragma unroll
        for (int d = 0; d < 64; d += 4) {
            alignas(16) float a[4][4];   // [i][dd]
            alignas(16) float bm[4][4];  // [dd][j]
            #pragma unroll
            for (int i = 0; i < 4; ++i)
                *(float4*)a[i] = *(const float4*)&Qs[ty * 4 + i][d];
            #pragma unroll
            for (int dd = 0; dd < 4; ++dd)
                *(float4*)bm[dd] = *(const float4*)&KT[d + dd][tx * 4];
            #pragma unroll
            for (int i = 0; i < 4; ++i)
                #pragma unroll
                for (int dd = 0; dd < 4; ++dd)
                    #pragma unroll
                    for (int j = 0; j < 4; ++j)
                        s[i][j] += a[i][dd] * bm[dd][j];
        }
        // apply mask
        #pragma unroll
        for (int i = 0; i < 4; ++i) {
            float4 mm = *(const float4*)(mask + (size_t)(n0 + ty * 4 + i) * N_PATCH + m0 + tx * 4);
            s[i][0] *= mm.x; s[i][1] *= mm.y; s[i][2] *= mm.z; s[i][3] *= mm.w;
        }
        __syncthreads();   // all threads finished reading KT
        #pragma unroll
        for (int i = 0; i < 4; ++i) {
            float4 sv; sv.x = s[i][0]; sv.y = s[i][1]; sv.z = s[i][2]; sv.w = s[i][3];
            *(float4*)&KT[ty * 4 + i][tx * 4] = sv;   // KT now holds S[n][m]
        }
        __syncthreads();

        if (tid < 64) {   // rowsum accumulate (wave 0)
            float rs = 0.f;
            #pragma unroll
            for (int m = 0; m < 64; ++m) rs += KT[tid][m];
            rowacc[tid] += rs;
        }

        // O += S @ V
        #pragma unroll
        for (int m = 0; m < 64; m += 4) {
            alignas(16) float sv[4][4];  // [i][mm]
            alignas(16) float vv[4][4];  // [mm][j]
            #pragma unroll
            for (int i = 0; i < 4; ++i)
                *(float4*)sv[i] = *(const float4*)&KT[ty * 4 + i][m];
            #pragma unroll
            for (int mm = 0; mm < 4; ++mm)
                *(float4*)vv[mm] = *(const float4*)&Vs[m + mm][tx * 4];
            #pragma unroll
            for (int i = 0; i < 4; ++i)
                #pragma unroll
                for (int mm = 0; mm < 4; ++mm)
                    #pragma unroll
                    for (int j = 0; j < 4; ++j)
                        oacc[i][j] += sv[i][mm] * vv[mm][j];
        }
    }
    __syncthreads();

    #pragma unroll
    for (int i = 0; i < 4; ++i) {
        int n = n0 + ty * 4 + i;
        float z = 1.f / (rowacc[ty * 4 + i] + EPS);
        float4 o;
        o.x = oacc[i][0] * z; o.y = oacc[i][1] * z;
        o.z = oacc[i][2] * z; o.w = oacc[i][3] * z;
        *(float4*)(attn + ((size_t)b * N_PATCH + n) * DIM + (size_t)h * HD + tx * 4) = o;
    }
}

// ---------------------------------------------------------------------------
extern "C" void kernel_launch(void* const* d_in, const int* in_sizes, int n_in,
                              void* d_out, int out_size, void* d_ws, size_t ws_size,
                              hipStream_t stream)
{
    (void)in_sizes; (void)n_in; (void)out_size; (void)ws_size;
    const float* x     = (const float*)d_in[0];   // [4,1024,768]
    const float* W_qkv = (const float*)d_in[1];   // [768,2304]
    const float* W_out = (const float*)d_in[2];   // [768,768]
    const float* b_out = (const float*)d_in[3];   // [768]
    const float* mask  = (const float*)d_in[4];   // [1024,1024]
    float* out = (float*)d_out;                   // [4,1024,768]

    float* ws   = (float*)d_ws;
    float* qkv  = ws;                                  // 4096*2304 = 9.44M floats
    float* qk2  = qkv + (size_t)4096 * TQ;             // 2*48*1024*64 = 6.29M floats
    float* attn = qk2 + (size_t)2 * 48 * N_PATCH * HD; // 4096*768  = 3.15M floats

    // 1) qkv = x @ W_qkv
    gemm_f32<false><<<dim3(TQ / 64, 4096 / 64), 256, 0, stream>>>(
        x, W_qkv, nullptr, qkv, 4096, DIM, TQ);
    // 2) q'' / k'' graph mix (+relu+eps fused)
    graphmix_kernel<<<dim3(N_PATCH / 64, NB * NH, 2), 256, 0, stream>>>(qkv, mask, qk2);
    // 3) masked linear attention
    attn_kernel<<<dim3(N_PATCH / 64, NB * NH), 256, 0, stream>>>(qk2, qkv, mask, attn);
    // 4) out = attn @ W_out + b_out
    gemm_f32<true><<<dim3(DIM / 64, 4096 / 64), 256, 0, stream>>>(
        attn, W_out, b_out, out, 4096, DIM, DIM);
}

// Round 2
// 188.033 us; speedup vs baseline: 3.6580x; 3.6580x over previous
//
#include <hip/hip_runtime.h>

#define NB   4
#define NP   1024
#define DIM  768
#define NH   12
#define HD   64
#define TQ   2304
#define EPS  1e-6f

typedef __attribute__((ext_vector_type(8))) short bf16x8;   // 8 bf16 in 4 VGPRs
typedef __attribute__((ext_vector_type(4))) float f32x4;

#define MFMA(a, b, c) __builtin_amdgcn_mfma_f32_16x16x32_bf16((a), (b), (c), 0, 0, 0)

__device__ __forceinline__ unsigned short f2b(float x) {       // fp32 -> bf16 RNE
    unsigned int u = __builtin_bit_cast(unsigned int, x);
    u = (u + 0x7fffu + ((u >> 16) & 1u)) >> 16;
    return (unsigned short)u;
}
__device__ __forceinline__ float b2f(unsigned short h) {
    unsigned int u = ((unsigned int)h) << 16;
    return __builtin_bit_cast(float, u);
}
__device__ __forceinline__ void gld16(const void* g, void* l) { // 16B global -> LDS
    __builtin_amdgcn_global_load_lds((const __attribute__((address_space(1))) unsigned int*)g,
                                     (__attribute__((address_space(3))) unsigned int*)l,
                                     16, 0, 0);
}

// --------------------------------------------------------------------------
// elementwise fp32 -> bf16 (8 elems/thread)
// --------------------------------------------------------------------------
__global__ __launch_bounds__(256) void k_convert(const float* __restrict__ in,
                                                 unsigned short* __restrict__ out, int n8) {
    int i = blockIdx.x * 256 + threadIdx.x;
    if (i >= n8) return;
    const float4* p = (const float4*)in + (size_t)i * 2;
    float4 a = p[0], b = p[1];
    alignas(16) unsigned short t[8] = {f2b(a.x), f2b(a.y), f2b(a.z), f2b(a.w),
                                       f2b(b.x), f2b(b.y), f2b(b.z), f2b(b.w)};
    *(uint4*)(out + (size_t)i * 8) = *(const uint4*)t;
}

// --------------------------------------------------------------------------
// transpose fp32 [R][C] -> bf16 [C][R]
// --------------------------------------------------------------------------
__global__ __launch_bounds__(256) void k_transpose(const float* __restrict__ in,
                                                   unsigned short* __restrict__ out,
                                                   int R, int C) {
    __shared__ float buf[64][65];
    const int r0 = blockIdx.y * 64, c0 = blockIdx.x * 64;
    const int t = threadIdx.x;
    const int rr = t >> 4, cc = (t & 15) * 4;
    #pragma unroll
    for (int p = 0; p < 4; ++p) {
        float4 v = *(const float4*)(in + (size_t)(r0 + p * 16 + rr) * C + c0 + cc);
        buf[p * 16 + rr][cc + 0] = v.x; buf[p * 16 + rr][cc + 1] = v.y;
        buf[p * 16 + rr][cc + 2] = v.z; buf[p * 16 + rr][cc + 3] = v.w;
    }
    __syncthreads();
    const int oc = t >> 2, orr = (t & 3) * 16;
    alignas(16) unsigned short tmp[16];
    #pragma unroll
    for (int j = 0; j < 16; ++j) tmp[j] = f2b(buf[orr + j][oc]);
    unsigned short* dst = out + (size_t)(c0 + oc) * R + r0 + orr;
    *(uint4*)dst = *(const uint4*)tmp;
    *(uint4*)(dst + 8) = *(const uint4*)(tmp + 8);
}

// --------------------------------------------------------------------------
// bf16 MFMA GEMM: C[M,N] = A[M,K] @ Bt[N,K]^T  (m97 structure: 128x128, BK=32)
// --------------------------------------------------------------------------
template <bool OUT_BF16, bool BIAS>
__global__ __launch_bounds__(256) void k_gemm(const unsigned short* __restrict__ A,
                                              const unsigned short* __restrict__ Bt,
                                              const float* __restrict__ bias,
                                              void* __restrict__ Cout,
                                              int M, int N, int K) {
    __shared__ unsigned short As[128][32];
    __shared__ unsigned short Bs[128][32];
    const int tid = threadIdx.x;
    const int w = tid >> 6, l = tid & 63;
    const int m0 = blockIdx.y * 128, n0 = blockIdx.x * 128;
    const int wm = (w >> 1) * 64, wn = (w & 1) * 64;
    const int quad = l >> 4, col = l & 15;
    const int lr = l >> 2, lc = (l & 3) * 8;

    f32x4 acc[4][4] = {};

    for (int k0 = 0; k0 < K; k0 += 32) {
        gld16(A + (size_t)(m0 + w * 32 + lr) * K + k0 + lc, &As[w * 32][0]);
        gld16(A + (size_t)(m0 + w * 32 + 16 + lr) * K + k0 + lc, &As[w * 32 + 16][0]);
        gld16(Bt + (size_t)(n0 + w * 32 + lr) * K + k0 + lc, &Bs[w * 32][0]);
        gld16(Bt + (size_t)(n0 + w * 32 + 16 + lr) * K + k0 + lc, &Bs[w * 32 + 16][0]);
        __syncthreads();
        bf16x8 a[4], b[4];
        #pragma unroll
        for (int i = 0; i < 4; ++i) a[i] = *(const bf16x8*)&As[wm + i * 16 + col][quad * 8];
        #pragma unroll
        for (int j = 0; j < 4; ++j) b[j] = *(const bf16x8*)&Bs[wn + j * 16 + col][quad * 8];
        #pragma unroll
        for (int i = 0; i < 4; ++i)
            #pragma unroll
            for (int j = 0; j < 4; ++j)
                acc[i][j] = MFMA(a[i], b[j], acc[i][j]);
        __syncthreads();
    }

    #pragma unroll
    for (int i = 0; i < 4; ++i) {
        #pragma unroll
        for (int j = 0; j < 4; ++j) {
            const int n = n0 + wn + j * 16 + col;
            #pragma unroll
            for (int r = 0; r < 4; ++r) {
                const int m = m0 + wm + i * 16 + quad * 4 + r;
                if (OUT_BF16) {
                    ((unsigned short*)Cout)[(size_t)m * N + n] = f2b(acc[i][j][r]);
                } else {
                    float v = acc[i][j][r];
                    if (BIAS) v += bias[n];
                    ((float*)Cout)[(size_t)m * N + n] = v;
                }
            }
        }
    }
}

// --------------------------------------------------------------------------
// qkv bf16 [B][N][3C] -> T[slot][bh][d(64)][n(1024)] bf16, relu+eps on q,k
// --------------------------------------------------------------------------
__global__ __launch_bounds__(256) void k_tqkv(const unsigned short* __restrict__ qkvb,
                                              unsigned short* __restrict__ T) {
    const int slot = blockIdx.z;                  // 0=q 1=k 2=v
    const int bh = blockIdx.y, b = bh / NH, h = bh % NH;
    const int n0 = blockIdx.x * 64;
    __shared__ unsigned short buf[64][72];
    const int t = threadIdx.x;
    const int rr = t >> 4, cc = (t & 15) * 4;
    const unsigned short* src = qkvb + (size_t)b * NP * TQ + slot * DIM + h * HD;
    const bool act = (slot < 2);
    #pragma unroll
    for (int p = 0; p < 4; ++p) {
        ushort4 v = *(const ushort4*)(src + (size_t)(n0 + p * 16 + rr) * TQ + cc);
        if (act) {
            v.x = f2b(fmaxf(b2f(v.x), 0.f) + EPS);
            v.y = f2b(fmaxf(b2f(v.y), 0.f) + EPS);
            v.z = f2b(fmaxf(b2f(v.z), 0.f) + EPS);
            v.w = f2b(fmaxf(b2f(v.w), 0.f) + EPS);
        }
        *(ushort4*)&buf[p * 16 + rr][cc] = v;
    }
    __syncthreads();
    const int od = t >> 2, on = (t & 3) * 16;
    alignas(16) unsigned short tmp[16];
    #pragma unroll
    for (int j = 0; j < 16; ++j) tmp[j] = buf[on + j][od];
    unsigned short* dst = T + ((size_t)(slot * 48 + bh) * HD + od) * NP + n0 + on;
    *(uint4*)dst = *(const uint4*)tmp;
    *(uint4*)(dst + 8) = *(const uint4*)(tmp + 8);
}

// --------------------------------------------------------------------------
// graphmix: q2[which][bh][m][d] = f(m,d) + 0.1 * sum_n mask[n,m] f(n,d)
// band: m covers grid rows {2mt, 2mt+1}; n restricted to rows [2mt-5, 2mt+6]
// --------------------------------------------------------------------------
__global__ __launch_bounds__(256) void k_graphmix(const unsigned short* __restrict__ maskT,
                                                  const unsigned short* __restrict__ T,
                                                  const unsigned short* __restrict__ qkvb,
                                                  unsigned short* __restrict__ q2) {
    const int which = blockIdx.z;
    const int bh = blockIdx.y, b = bh / NH, h = bh % NH;
    const int m0 = blockIdx.x * 64;
    __shared__ unsigned short Ms[64][32];
    __shared__ unsigned short Fs[64][32];
    const int tid = threadIdx.x, w = tid >> 6, l = tid & 63;
    const int quad = l >> 4, col = l & 15;
    const int lr = l >> 2, lc = (l & 3) * 8;
    const unsigned short* Fb = T + (size_t)(which * 48 + bh) * HD * NP;

    const int gr = 2 * blockIdx.x;
    const int r0 = max(0, gr - 5), r1 = min(31, gr + 6);

    f32x4 acc[4] = {};
    for (int rw = r0; rw <= r1; ++rw) {
        const int n0 = rw * 32;
        gld16(maskT + (size_t)(m0 + w * 16 + lr) * NP + n0 + lc, &Ms[w * 16][0]);
        gld16(Fb + (size_t)(w * 16 + lr) * NP + n0 + lc, &Fs[w * 16][0]);
        __syncthreads();
        bf16x8 a = *(const bf16x8*)&Ms[w * 16 + col][quad * 8];
        #pragma unroll
        for (int dt = 0; dt < 4; ++dt) {
            bf16x8 bfr = *(const bf16x8*)&Fs[dt * 16 + col][quad * 8];
            acc[dt] = MFMA(a, bfr, acc[dt]);
        }
        __syncthreads();
    }

    const unsigned short* qsrc = qkvb + (size_t)b * NP * TQ + which * DIM + h * HD;
    unsigned short* dst = q2 + (size_t)((which * 48 + bh) * NP + m0) * HD;
    #pragma unroll
    for (int r = 0; r < 4; ++r) {
        const int m = w * 16 + quad * 4 + r;
        #pragma unroll
        for (int dt = 0; dt < 4; ++dt) {
            const int d = dt * 16 + col;
            float f = fmaxf(b2f(qsrc[(size_t)(m0 + m) * TQ + d]), 0.f) + EPS;
            dst[(size_t)m * HD + d] = f2b(f + 0.1f * acc[dt][r]);
        }
    }
}

// --------------------------------------------------------------------------
// attention: per (bh, n-tile 64): loop m-tiles in band [nt-3, nt+3]:
//   S = (Q K^T) * mask ; racc += rowsum(S) ; O += S @ V ; epilogue O / racc
// --------------------------------------------------------------------------
__global__ __launch_bounds__(256) void k_attn(const unsigned short* __restrict__ q2,
                                              const unsigned short* __restrict__ T,
                                              const float* __restrict__ mask,
                                              unsigned short* __restrict__ attnb) {
    const int bh = blockIdx.y, b = bh / NH, h = bh % NH;
    const int nt = blockIdx.x, n0 = nt * 64;
    __shared__ unsigned short Qs[64][64];
    __shared__ unsigned short Ks[64][64];
    __shared__ unsigned short VTs[64][64];
    __shared__ unsigned short Ss[64][64];
    __shared__ float rowz[64];
    const int tid = threadIdx.x, w = tid >> 6, l = tid & 63;
    const int quad = l >> 4, col = l & 15;
    const int lr8 = l >> 3, lc8 = (l & 7) * 8;

    const unsigned short* qb = q2 + (size_t)(bh * NP + n0) * HD;
    gld16(qb + (size_t)(w * 16 + lr8) * HD + lc8, &Qs[w * 16][0]);
    gld16(qb + (size_t)(w * 16 + 8 + lr8) * HD + lc8, &Qs[w * 16 + 8][0]);

    const unsigned short* kb = q2 + (size_t)(48 + bh) * NP * HD;
    const unsigned short* vtb = T + (size_t)(2 * 48 + bh) * HD * NP;

    f32x4 oacc[4] = {};
    float racc[4] = {0.f, 0.f, 0.f, 0.f};
    const int mlo = max(0, nt - 3), mhi = min(15, nt + 3);

    for (int mt = mlo; mt <= mhi; ++mt) {
        const int m0 = mt * 64;
        __syncthreads();
        gld16(kb + (size_t)(m0 + w * 16 + lr8) * HD + lc8, &Ks[w * 16][0]);
        gld16(kb + (size_t)(m0 + w * 16 + 8 + lr8) * HD + lc8, &Ks[w * 16 + 8][0]);
        gld16(vtb + (size_t)(w * 16 + lr8) * NP + m0 + lc8, &VTs[w * 16][0]);
        gld16(vtb + (size_t)(w * 16 + 8 + lr8) * NP + m0 + lc8, &VTs[w * 16 + 8][0]);
        __syncthreads();

        // S = Q @ K^T  (D rows = n, cols = m)
        f32x4 s[4] = {};
        #pragma unroll
        for (int ks = 0; ks < 2; ++ks) {
            bf16x8 aq = *(const bf16x8*)&Qs[w * 16 + col][ks * 32 + quad * 8];
            #pragma unroll
            for (int mtt = 0; mtt < 4; ++mtt) {
                bf16x8 bk = *(const bf16x8*)&Ks[mtt * 16 + col][ks * 32 + quad * 8];
                s[mtt] = MFMA(aq, bk, s[mtt]);
            }
        }
        // mask (fp32) + rowsum accumulate + store S (bf16) for the PV matmul
        #pragma unroll
        for (int mtt = 0; mtt < 4; ++mtt) {
            #pragma unroll
            for (int r = 0; r < 4; ++r) {
                const int n = n0 + w * 16 + quad * 4 + r;
                const int m = m0 + mtt * 16 + col;
                float v = s[mtt][r] * mask[(size_t)n * NP + m];
                racc[r] += v;
                Ss[w * 16 + quad * 4 + r][mtt * 16 + col] = f2b(v);
            }
        }
        __syncthreads();
        // O += S @ V  (B operand from V^T tile)
        #pragma unroll
        for (int ks = 0; ks < 2; ++ks) {
            bf16x8 as = *(const bf16x8*)&Ss[w * 16 + col][ks * 32 + quad * 8];
            #pragma unroll
            for (int dt = 0; dt < 4; ++dt) {
                bf16x8 bv = *(const bf16x8*)&VTs[dt * 16 + col][ks * 32 + quad * 8];
                oacc[dt] = MFMA(as, bv, oacc[dt]);
            }
        }
    }

    // reduce rowsum across the 16 lanes of each quad-group
    #pragma unroll
    for (int r = 0; r < 4; ++r) {
        float v = racc[r];
        v += __shfl_xor(v, 1); v += __shfl_xor(v, 2);
        v += __shfl_xor(v, 4); v += __shfl_xor(v, 8);
        if (col == 0) rowz[w * 16 + quad * 4 + r] = v;
    }
    __syncthreads();

    unsigned short* ob = attnb + ((size_t)b * NP + n0) * DIM + h * HD;
    #pragma unroll
    for (int r = 0; r < 4; ++r) {
        const int nl = w * 16 + quad * 4 + r;
        const float z = 1.f / (rowz[nl] + EPS);
        #pragma unroll
        for (int dt = 0; dt < 4; ++dt)
            ob[(size_t)nl * DIM + dt * 16 + col] = f2b(oacc[dt][r] * z);
    }
}

// --------------------------------------------------------------------------
extern "C" void kernel_launch(void* const* d_in, const int* in_sizes, int n_in,
                              void* d_out, int out_size, void* d_ws, size_t ws_size,
                              hipStream_t stream) {
    (void)in_sizes; (void)n_in; (void)out_size; (void)ws_size;
    const float* x     = (const float*)d_in[0];
    const float* W_qkv = (const float*)d_in[1];
    const float* W_out = (const float*)d_in[2];
    const float* b_out = (const float*)d_in[3];
    const float* mask  = (const float*)d_in[4];
    float* out = (float*)d_out;

    unsigned short* p = (unsigned short*)d_ws;
    unsigned short* xb     = p; p += (size_t)4096 * DIM;          // 3.1M
    unsigned short* WqkvT  = p; p += (size_t)TQ * DIM;            // 1.8M
    unsigned short* WoutT  = p; p += (size_t)DIM * DIM;           // 0.6M
    unsigned short* maskT  = p; p += (size_t)NP * NP;             // 1.0M
    unsigned short* qkvb   = p; p += (size_t)4096 * TQ;           // 9.4M
    unsigned short* T      = p; p += (size_t)3 * 48 * HD * NP;    // 9.4M
    unsigned short* q2     = p; p += (size_t)2 * 48 * NP * HD;    // 6.3M
    unsigned short* attnb  = p; p += (size_t)4096 * DIM;          // 3.1M

    // converts / transposes
    k_convert<<<dim3(4096 * DIM / 8 / 256), 256, 0, stream>>>(x, xb, 4096 * DIM / 8);
    k_transpose<<<dim3(TQ / 64, DIM / 64), 256, 0, stream>>>(W_qkv, WqkvT, DIM, TQ);
    k_transpose<<<dim3(DIM / 64, DIM / 64), 256, 0, stream>>>(W_out, WoutT, DIM, DIM);
    k_transpose<<<dim3(NP / 64, NP / 64), 256, 0, stream>>>(mask, maskT, NP, NP);
    // qkv = x @ W_qkv (bf16 out)
    k_gemm<true, false><<<dim3(TQ / 128, 4096 / 128), 256, 0, stream>>>(
        xb, WqkvT, nullptr, qkvb, 4096, TQ, DIM);
    // transposed f(q), f(k), v
    k_tqkv<<<dim3(NP / 64, 48, 3), 256, 0, stream>>>(qkvb, T);
    // graph mix
    k_graphmix<<<dim3(NP / 64, 48, 2), 256, 0, stream>>>(maskT, T, qkvb, q2);
    // masked linear attention
    k_attn<<<dim3(NP / 64, 48), 256, 0, stream>>>(q2, T, mask, attnb);
    // out = attn @ W_out + b_out (fp32 out)
    k_gemm<false, true><<<dim3(DIM / 128, 4096 / 128), 256, 0, stream>>>(
        attnb, WoutT, b_out, out, 4096, DIM, DIM);
}

// Round 3
// 179.472 us; speedup vs baseline: 3.8325x; 1.0477x over previous
//
#include <hip/hip_runtime.h>

#define NP   1024
#define DIM  768
#define NH   12
#define HD   64
#define TQ   2304
#define EPS  1e-6f

typedef __attribute__((ext_vector_type(8))) short bf16x8;
typedef __attribute__((ext_vector_type(4))) float f32x4;

#define MFMA(a, b, c) __builtin_amdgcn_mfma_f32_16x16x32_bf16((a), (b), (c), 0, 0, 0)

__device__ __forceinline__ unsigned short f2b(float x) {       // fp32 -> bf16 RNE
    unsigned int u = __builtin_bit_cast(unsigned int, x);
    u = (u + 0x7fffu + ((u >> 16) & 1u)) >> 16;
    return (unsigned short)u;
}
__device__ __forceinline__ float b2f(unsigned short h) {
    unsigned int u = ((unsigned int)h) << 16;
    return __builtin_bit_cast(float, u);
}
__device__ __forceinline__ void gld16(const void* g, void* l) { // 16B global -> LDS
    __builtin_amdgcn_global_load_lds((const __attribute__((address_space(1))) unsigned int*)g,
                                     (__attribute__((address_space(3))) unsigned int*)l,
                                     16, 0, 0);
}

// --------------------------------------------------------------------------
// fused prep: convert x -> bf16 ; transpose W_qkv, W_out, mask -> bf16
// --------------------------------------------------------------------------
__global__ __launch_bounds__(256) void k_prep(const float* __restrict__ x,
                                              const float* __restrict__ W_qkv,
                                              const float* __restrict__ W_out,
                                              const float* __restrict__ mask,
                                              unsigned short* __restrict__ xb,
                                              unsigned short* __restrict__ WqkvT,
                                              unsigned short* __restrict__ WoutT,
                                              unsigned short* __restrict__ maskT) {
    __shared__ float buf[64][65];
    const int bx = blockIdx.x, t = threadIdx.x;
    if (bx < 1536) {                       // convert x (4096*768 elems, 8/thread)
        const int i = bx * 256 + t;
        const float4* p = (const float4*)x + (size_t)i * 2;
        float4 a = p[0], b = p[1];
        alignas(16) unsigned short o[8] = {f2b(a.x), f2b(a.y), f2b(a.z), f2b(a.w),
                                           f2b(b.x), f2b(b.y), f2b(b.z), f2b(b.w)};
        *(uint4*)(xb + (size_t)i * 8) = *(const uint4*)o;
        return;
    }
    const float* in; unsigned short* outp; int R, C, ct, rt;
    if (bx < 1968)      { int q = bx - 1536; in = W_qkv; outp = WqkvT; R = 768;  C = 2304; ct = q % 36; rt = q / 36; }
    else if (bx < 2112) { int q = bx - 1968; in = W_out; outp = WoutT; R = 768;  C = 768;  ct = q % 12; rt = q / 12; }
    else                { int q = bx - 2112; in = mask;  outp = maskT; R = 1024; C = 1024; ct = q % 16; rt = q / 16; }
    const int r0 = rt * 64, c0 = ct * 64;
    const int rr = t >> 4, cc = (t & 15) * 4;
    #pragma unroll
    for (int p = 0; p < 4; ++p) {
        float4 v = *(const float4*)(in + (size_t)(r0 + p * 16 + rr) * C + c0 + cc);
        buf[p * 16 + rr][cc + 0] = v.x; buf[p * 16 + rr][cc + 1] = v.y;
        buf[p * 16 + rr][cc + 2] = v.z; buf[p * 16 + rr][cc + 3] = v.w;
    }
    __syncthreads();
    const int oc = t >> 2, orr = (t & 3) * 16;
    alignas(16) unsigned short tmp[16];
    #pragma unroll
    for (int j = 0; j < 16; ++j) tmp[j] = f2b(buf[orr + j][oc]);
    unsigned short* dst = outp + (size_t)(c0 + oc) * R + r0 + orr;
    *(uint4*)dst = *(const uint4*)tmp;
    *(uint4*)(dst + 8) = *(const uint4*)(tmp + 8);
}

// --------------------------------------------------------------------------
// gemm1: qkv = xb @ WqkvT^T, epilogue writes ONLY the transposed layout
// T[slot*48 + b*12 + h][d][np]  with relu+eps fused on q,k slots.
// --------------------------------------------------------------------------
__global__ __launch_bounds__(256) void k_gemm1(const unsigned short* __restrict__ A,
                                               const unsigned short* __restrict__ Bt,
                                               unsigned short* __restrict__ T) {
    __shared__ unsigned short As[128][32];
    __shared__ unsigned short Bs[128][32];
    __shared__ unsigned short Es[128][136];
    const int tid = threadIdx.x, w = tid >> 6, l = tid & 63;
    const int m0 = blockIdx.y * 128, n0 = blockIdx.x * 128;
    const int wm = (w >> 1) * 64, wn = (w & 1) * 64;
    const int quad = l >> 4, col = l & 15;
    const int lr = l >> 2, lc = (l & 3) * 8;

    f32x4 acc[4][4] = {};
    for (int k0 = 0; k0 < DIM; k0 += 32) {
        gld16(A + (size_t)(m0 + w * 32 + lr) * DIM + k0 + lc, &As[w * 32][0]);
        gld16(A + (size_t)(m0 + w * 32 + 16 + lr) * DIM + k0 + lc, &As[w * 32 + 16][0]);
        gld16(Bt + (size_t)(n0 + w * 32 + lr) * DIM + k0 + lc, &Bs[w * 32][0]);
        gld16(Bt + (size_t)(n0 + w * 32 + 16 + lr) * DIM + k0 + lc, &Bs[w * 32 + 16][0]);
        __syncthreads();
        bf16x8 a[4], b[4];
        #pragma unroll
        for (int i = 0; i < 4; ++i) a[i] = *(const bf16x8*)&As[wm + i * 16 + col][quad * 8];
        #pragma unroll
        for (int j = 0; j < 4; ++j) b[j] = *(const bf16x8*)&Bs[wn + j * 16 + col][quad * 8];
        #pragma unroll
        for (int i = 0; i < 4; ++i)
            #pragma unroll
            for (int j = 0; j < 4; ++j)
                acc[i][j] = MFMA(a[i], b[j], acc[i][j]);
        __syncthreads();
    }

    const int slot = n0 / DIM;            // tile never straddles slots (768%128==0)
    const bool act = (slot < 2);
    #pragma unroll
    for (int i = 0; i < 4; ++i)
        #pragma unroll
        for (int j = 0; j < 4; ++j)
            #pragma unroll
            for (int r = 0; r < 4; ++r) {
                float v = acc[i][j][r];
                if (act) v = fmaxf(v, 0.f) + EPS;
                Es[wn + j * 16 + col][wm + i * 16 + quad * 4 + r] = f2b(v);
            }
    __syncthreads();
    const int row = tid >> 1, halfm = (tid & 1) * 64;
    const int cg = n0 + row;
    const int sh = slot * 48 + (blockIdx.y >> 3) * NH + ((cg % DIM) >> 6);
    const int d = cg & 63;
    const int np0 = (blockIdx.y & 7) * 128;
    unsigned short* dst = T + ((size_t)sh * HD + d) * NP + np0 + halfm;
    #pragma unroll
    for (int tt = 0; tt < 8; ++tt)
        *(uint4*)(dst + tt * 8) = *(const uint4*)&Es[row][halfm + tt * 8];
}

// --------------------------------------------------------------------------
// graphmix (q and k fused, mask tile shared):
//   q2[which][bh][m][d] = f(m,d) + 0.1 * sum_n mask[n,m] f(n,d)
// band: n grid-rows [2mt-5, 2mt+6]. f addend grabbed from the band's own
// staged tiles (Sq/Sk saves) — no row-major qkv needed.
// --------------------------------------------------------------------------
__global__ __launch_bounds__(256) void k_graphmix(const unsigned short* __restrict__ maskT,
                                                  const unsigned short* __restrict__ T,
                                                  unsigned short* __restrict__ q2) {
    const int bh = blockIdx.y, mt = blockIdx.x;
    const int m0 = mt * 64, gr = 2 * mt;
    __shared__ unsigned short Ms[64][32], Fq[64][32], Fk[64][32];
    __shared__ unsigned short Sq[64][72], Sk[64][72];
    const int tid = threadIdx.x, w = tid >> 6, l = tid & 63;
    const int quad = l >> 4, col = l & 15;
    const int lr = l >> 2, lc = (l & 3) * 8;
    const unsigned short* Tq = T + (size_t)bh * HD * NP;
    const unsigned short* Tk = T + (size_t)(48 + bh) * HD * NP;

    f32x4 accq[4] = {}, acck[4] = {};
    const int r0 = max(0, gr - 5), r1 = min(31, gr + 6);
    for (int rw = r0; rw <= r1; ++rw) {
        const int nc = rw * 32;
        __syncthreads();
        gld16(maskT + (size_t)(m0 + w * 16 + lr) * NP + nc + lc, &Ms[w * 16][0]);
        gld16(Tq + (size_t)(w * 16 + lr) * NP + nc + lc, &Fq[w * 16][0]);
        gld16(Tk + (size_t)(w * 16 + lr) * NP + nc + lc, &Fk[w * 16][0]);
        __syncthreads();
        if (rw == gr || rw == gr + 1) {       // save f tiles covering our m-range
            const int off = (rw - gr) * 32;
            *(uint4*)&Sq[w * 16 + lr][off + lc] = *(const uint4*)&Fq[w * 16 + lr][lc];
            *(uint4*)&Sk[w * 16 + lr][off + lc] = *(const uint4*)&Fk[w * 16 + lr][lc];
        }
        bf16x8 a = *(const bf16x8*)&Ms[w * 16 + col][quad * 8];
        #pragma unroll
        for (int dt = 0; dt < 4; ++dt) {
            accq[dt] = MFMA(a, *(const bf16x8*)&Fq[dt * 16 + col][quad * 8], accq[dt]);
            acck[dt] = MFMA(a, *(const bf16x8*)&Fk[dt * 16 + col][quad * 8], acck[dt]);
        }
    }
    __syncthreads();
    unsigned short* q2q = q2 + ((size_t)bh * NP + m0) * HD;
    unsigned short* q2k = q2 + ((size_t)(48 + bh) * NP + m0) * HD;
    #pragma unroll
    for (int dt = 0; dt < 4; ++dt)
        #pragma unroll
        for (int r = 0; r < 4; ++r) {
            const int ml = w * 16 + quad * 4 + r;
            const int d = dt * 16 + col;
            q2q[(size_t)ml * HD + d] = f2b(b2f(Sq[d][ml]) + 0.1f * accq[dt][r]);
            q2k[(size_t)ml * HD + d] = f2b(b2f(Sk[d][ml]) + 0.1f * acck[dt][r]);
        }
}

// --------------------------------------------------------------------------
// attention: 128-row Q tiles; band m-tiles [2nt2-3, 2nt2+4]; half-K split
// LDS buffers (64B rows -> 2-way conflict-free b128 frag reads).
// --------------------------------------------------------------------------
__global__ __launch_bounds__(256) void k_attn(const unsigned short* __restrict__ q2,
                                              const unsigned short* __restrict__ T,
                                              const float* __restrict__ mask,
                                              unsigned short* __restrict__ attnb) {
    const int bh = blockIdx.y, b = bh / NH, h = bh % NH;
    const int nt2 = blockIdx.x, n0 = nt2 * 128;
    __shared__ unsigned short Qs[2][128][32];
    __shared__ unsigned short Ks[2][64][32];
    __shared__ unsigned short VT[2][64][32];
    __shared__ unsigned short Ss[128][72];
    __shared__ float rowz[128];
    const int tid = threadIdx.x, w = tid >> 6, l = tid & 63;
    const int quad = l >> 4, col = l & 15;
    const int lr = l >> 2, lc = (l & 3) * 8;

    const unsigned short* qb = q2 + ((size_t)bh * NP + n0) * HD;
    const unsigned short* kb = q2 + (size_t)(48 + bh) * NP * HD;
    const unsigned short* vtb = T + (size_t)(96 + bh) * HD * NP;

    #pragma unroll
    for (int hh = 0; hh < 2; ++hh)
        #pragma unroll
        for (int c = 0; c < 2; ++c)
            gld16(qb + (size_t)(w * 32 + c * 16 + lr) * HD + hh * 32 + lc,
                  &Qs[hh][w * 32 + c * 16][0]);

    f32x4 oacc[2][4] = {};
    float racc[2][4] = {};
    const int mlo = max(0, 2 * nt2 - 3), mhi = min(15, 2 * nt2 + 4);

    for (int mt = mlo; mt <= mhi; ++mt) {
        const int m0 = mt * 64;
        float mreg[2][4][4];               // prefetch mask into regs pre-barrier
        #pragma unroll
        for (int rg = 0; rg < 2; ++rg)
            #pragma unroll
            for (int mtt = 0; mtt < 4; ++mtt)
                #pragma unroll
                for (int r = 0; r < 4; ++r)
                    mreg[rg][mtt][r] = mask[(size_t)(n0 + (w * 2 + rg) * 16 + quad * 4 + r) * NP
                                            + m0 + mtt * 16 + col];
        __syncthreads();                   // prior iter's Ks/VT/Ss reads done
        #pragma unroll
        for (int hh = 0; hh < 2; ++hh) {
            gld16(kb + (size_t)(m0 + w * 16 + lr) * HD + hh * 32 + lc, &Ks[hh][w * 16][0]);
            gld16(vtb + (size_t)(w * 16 + lr) * NP + m0 + hh * 32 + lc, &VT[hh][w * 16][0]);
        }
        __syncthreads();

        f32x4 s[2][4] = {};
        #pragma unroll
        for (int ks = 0; ks < 2; ++ks) {
            bf16x8 bk[4];
            #pragma unroll
            for (int mtt = 0; mtt < 4; ++mtt) bk[mtt] = *(const bf16x8*)&Ks[ks][mtt * 16 + col][quad * 8];
            #pragma unroll
            for (int rg = 0; rg < 2; ++rg) {
                bf16x8 aq = *(const bf16x8*)&Qs[ks][(w * 2 + rg) * 16 + col][quad * 8];
                #pragma unroll
                for (int mtt = 0; mtt < 4; ++mtt) s[rg][mtt] = MFMA(aq, bk[mtt], s[rg][mtt]);
            }
        }
        #pragma unroll
        for (int rg = 0; rg < 2; ++rg)
            #pragma unroll
            for (int mtt = 0; mtt < 4; ++mtt)
                #pragma unroll
                for (int r = 0; r < 4; ++r) {
                    float v = s[rg][mtt][r] * mreg[rg][mtt][r];
                    racc[rg][r] += v;
                    Ss[(w * 2 + rg) * 16 + quad * 4 + r][mtt * 16 + col] = f2b(v);
                }
        __syncthreads();
        #pragma unroll
        for (int ks = 0; ks < 2; ++ks) {
            bf16x8 bv[4];
            #pragma unroll
            for (int dt = 0; dt < 4; ++dt) bv[dt] = *(const bf16x8*)&VT[ks][dt * 16 + col][quad * 8];
            #pragma unroll
            for (int rg = 0; rg < 2; ++rg) {
                bf16x8 as = *(const bf16x8*)&Ss[(w * 2 + rg) * 16 + col][ks * 32 + quad * 8];
                #pragma unroll
                for (int dt = 0; dt < 4; ++dt) oacc[rg][dt] = MFMA(as, bv[dt], oacc[rg][dt]);
            }
        }
    }

    #pragma unroll
    for (int rg = 0; rg < 2; ++rg)
        #pragma unroll
        for (int r = 0; r < 4; ++r) {
            float v = racc[rg][r];
            v += __shfl_xor(v, 1); v += __shfl_xor(v, 2);
            v += __shfl_xor(v, 4); v += __shfl_xor(v, 8);
            if (col == 0) rowz[(w * 2 + rg) * 16 + quad * 4 + r] = v;
        }
    __syncthreads();
    #pragma unroll
    for (int rg = 0; rg < 2; ++rg)
        #pragma unroll
        for (int r = 0; r < 4; ++r) {
            const int nl = (w * 2 + rg) * 16 + quad * 4 + r;
            const float z = 1.f / (rowz[nl] + EPS);
            #pragma unroll
            for (int dt = 0; dt < 4; ++dt)
                attnb[(size_t)(b * NP + n0 + nl) * DIM + h * HD + dt * 16 + col] =
                    f2b(oacc[rg][dt][r] * z);
        }
}

// --------------------------------------------------------------------------
// gemm2: out = attnb @ WoutT^T + b_out (fp32 out)
// --------------------------------------------------------------------------
__global__ __launch_bounds__(256) void k_gemm2(const unsigned short* __restrict__ A,
                                               const unsigned short* __restrict__ Bt,
                                               const float* __restrict__ bias,
                                               float* __restrict__ C) {
    __shared__ unsigned short As[128][32];
    __shared__ unsigned short Bs[128][32];
    const int tid = threadIdx.x, w = tid >> 6, l = tid & 63;
    const int m0 = blockIdx.y * 128, n0 = blockIdx.x * 128;
    const int wm = (w >> 1) * 64, wn = (w & 1) * 64;
    const int quad = l >> 4, col = l & 15;
    const int lr = l >> 2, lc = (l & 3) * 8;

    f32x4 acc[4][4] = {};
    for (int k0 = 0; k0 < DIM; k0 += 32) {
        gld16(A + (size_t)(m0 + w * 32 + lr) * DIM + k0 + lc, &As[w * 32][0]);
        gld16(A + (size_t)(m0 + w * 32 + 16 + lr) * DIM + k0 + lc, &As[w * 32 + 16][0]);
        gld16(Bt + (size_t)(n0 + w * 32 + lr) * DIM + k0 + lc, &Bs[w * 32][0]);
        gld16(Bt + (size_t)(n0 + w * 32 + 16 + lr) * DIM + k0 + lc, &Bs[w * 32 + 16][0]);
        __syncthreads();
        bf16x8 a[4], b[4];
        #pragma unroll
        for (int i = 0; i < 4; ++i) a[i] = *(const bf16x8*)&As[wm + i * 16 + col][quad * 8];
        #pragma unroll
        for (int j = 0; j < 4; ++j) b[j] = *(const bf16x8*)&Bs[wn + j * 16 + col][quad * 8];
        #pragma unroll
        for (int i = 0; i < 4; ++i)
            #pragma unroll
            for (int j = 0; j < 4; ++j)
                acc[i][j] = MFMA(a[i], b[j], acc[i][j]);
        __syncthreads();
    }
    #pragma unroll
    for (int i = 0; i < 4; ++i)
        #pragma unroll
        for (int j = 0; j < 4; ++j) {
            const int n = n0 + wn + j * 16 + col;
            #pragma unroll
            for (int r = 0; r < 4; ++r) {
                const int m = m0 + wm + i * 16 + quad * 4 + r;
                C[(size_t)m * DIM + n] = acc[i][j][r] + bias[n];
            }
        }
}

// --------------------------------------------------------------------------
extern "C" void kernel_launch(void* const* d_in, const int* in_sizes, int n_in,
                              void* d_out, int out_size, void* d_ws, size_t ws_size,
                              hipStream_t stream) {
    (void)in_sizes; (void)n_in; (void)out_size; (void)ws_size;
    const float* x     = (const float*)d_in[0];
    const float* W_qkv = (const float*)d_in[1];
    const float* W_out = (const float*)d_in[2];
    const float* b_out = (const float*)d_in[3];
    const float* mask  = (const float*)d_in[4];
    float* out = (float*)d_out;

    unsigned short* p = (unsigned short*)d_ws;
    unsigned short* xb    = p; p += (size_t)4096 * DIM;
    unsigned short* WqkvT = p; p += (size_t)TQ * DIM;
    unsigned short* WoutT = p; p += (size_t)DIM * DIM;
    unsigned short* maskT = p; p += (size_t)NP * NP;
    unsigned short* T     = p; p += (size_t)3 * 48 * HD * NP;
    unsigned short* q2    = p; p += (size_t)2 * 48 * NP * HD;
    unsigned short* attnb = p; p += (size_t)4096 * DIM;

    k_prep<<<dim3(2368), 256, 0, stream>>>(x, W_qkv, W_out, mask, xb, WqkvT, WoutT, maskT);
    k_gemm1<<<dim3(TQ / 128, 4096 / 128), 256, 0, stream>>>(xb, WqkvT, T);
    k_graphmix<<<dim3(NP / 64, 48), 256, 0, stream>>>(maskT, T, q2);
    k_attn<<<dim3(NP / 128, 48), 256, 0, stream>>>(q2, T, mask, attnb);
    k_gemm2<<<dim3(DIM / 128, 4096 / 128), 256, 0, stream>>>(attnb, WoutT, b_out, out);
}

// Round 4
// 175.353 us; speedup vs baseline: 3.9225x; 1.0235x over previous
//
#include <hip/hip_runtime.h>

#define NP   1024
#define DIM  768
#define NH   12
#define HD   64
#define TQ   2304
#define EPS  1e-6f

typedef __attribute__((ext_vector_type(8))) short bf16x8;
typedef __attribute__((ext_vector_type(4))) float f32x4;

#define MFMA(a, b, c) __builtin_amdgcn_mfma_f32_16x16x32_bf16((a), (b), (c), 0, 0, 0)

__device__ __forceinline__ unsigned short f2b(float x) {       // fp32 -> bf16 RNE
    unsigned int u = __builtin_bit_cast(unsigned int, x);
    u = (u + 0x7fffu + ((u >> 16) & 1u)) >> 16;
    return (unsigned short)u;
}
__device__ __forceinline__ float b2f(unsigned short h) {
    unsigned int u = ((unsigned int)h) << 16;
    return __builtin_bit_cast(float, u);
}
__device__ __forceinline__ void gld16(const void* g, void* l) { // 16B global -> LDS
    __builtin_amdgcn_global_load_lds((const __attribute__((address_space(1))) unsigned int*)g,
                                     (__attribute__((address_space(3))) unsigned int*)l,
                                     16, 0, 0);
}

// --------------------------------------------------------------------------
// fused prep: convert x -> bf16 ; transpose W_qkv, W_out, mask -> bf16
// --------------------------------------------------------------------------
__global__ __launch_bounds__(256) void k_prep(const float* __restrict__ x,
                                              const float* __restrict__ W_qkv,
                                              const float* __restrict__ W_out,
                                              const float* __restrict__ mask,
                                              unsigned short* __restrict__ xb,
                                              unsigned short* __restrict__ WqkvT,
                                              unsigned short* __restrict__ WoutT,
                                              unsigned short* __restrict__ maskT) {
    __shared__ float buf[64][65];
    const int bx = blockIdx.x, t = threadIdx.x;
    if (bx < 1536) {                       // convert x (4096*768 elems, 8/thread)
        const int i = bx * 256 + t;
        const float4* p = (const float4*)x + (size_t)i * 2;
        float4 a = p[0], b = p[1];
        alignas(16) unsigned short o[8] = {f2b(a.x), f2b(a.y), f2b(a.z), f2b(a.w),
                                           f2b(b.x), f2b(b.y), f2b(b.z), f2b(b.w)};
        *(uint4*)(xb + (size_t)i * 8) = *(const uint4*)o;
        return;
    }
    const float* in; unsigned short* outp; int R, C, ct, rt;
    if (bx < 1968)      { int q = bx - 1536; in = W_qkv; outp = WqkvT; R = 768;  C = 2304; ct = q % 36; rt = q / 36; }
    else if (bx < 2112) { int q = bx - 1968; in = W_out; outp = WoutT; R = 768;  C = 768;  ct = q % 12; rt = q / 12; }
    else                { int q = bx - 2112; in = mask;  outp = maskT; R = 1024; C = 1024; ct = q % 16; rt = q / 16; }
    const int r0 = rt * 64, c0 = ct * 64;
    const int rr = t >> 4, cc = (t & 15) * 4;
    #pragma unroll
    for (int p = 0; p < 4; ++p) {
        float4 v = *(const float4*)(in + (size_t)(r0 + p * 16 + rr) * C + c0 + cc);
        buf[p * 16 + rr][cc + 0] = v.x; buf[p * 16 + rr][cc + 1] = v.y;
        buf[p * 16 + rr][cc + 2] = v.z; buf[p * 16 + rr][cc + 3] = v.w;
    }
    __syncthreads();
    const int oc = t >> 2, orr = (t & 3) * 16;
    alignas(16) unsigned short tmp[16];
    #pragma unroll
    for (int j = 0; j < 16; ++j) tmp[j] = f2b(buf[orr + j][oc]);
    unsigned short* dst = outp + (size_t)(c0 + oc) * R + r0 + orr;
    *(uint4*)dst = *(const uint4*)tmp;
    *(uint4*)(dst + 8) = *(const uint4*)(tmp + 8);
}

// --------------------------------------------------------------------------
// gemm1: qkv = xb @ WqkvT^T; epilogue stores fragments DIRECTLY to the
// transposed layout T[slot*48 + b*12 + h][d][np] (relu+eps fused on q,k).
// MFMA C/D layout gives each lane 4 consecutive m (=np) values -> one
// packed 8B store per fragment. No LDS bounce.
// --------------------------------------------------------------------------
__global__ __launch_bounds__(256) void k_gemm1(const unsigned short* __restrict__ A,
                                               const unsigned short* __restrict__ Bt,
                                               unsigned short* __restrict__ T) {
    __shared__ unsigned short As[128][32];
    __shared__ unsigned short Bs[128][32];
    const int tid = threadIdx.x, w = tid >> 6, l = tid & 63;
    const int m0 = blockIdx.y * 128, n0 = blockIdx.x * 128;
    const int wm = (w >> 1) * 64, wn = (w & 1) * 64;
    const int quad = l >> 4, col = l & 15;
    const int lr = l >> 2, lc = (l & 3) * 8;

    f32x4 acc[4][4] = {};
    for (int k0 = 0; k0 < DIM; k0 += 32) {
        gld16(A + (size_t)(m0 + w * 32 + lr) * DIM + k0 + lc, &As[w * 32][0]);
        gld16(A + (size_t)(m0 + w * 32 + 16 + lr) * DIM + k0 + lc, &As[w * 32 + 16][0]);
        gld16(Bt + (size_t)(n0 + w * 32 + lr) * DIM + k0 + lc, &Bs[w * 32][0]);
        gld16(Bt + (size_t)(n0 + w * 32 + 16 + lr) * DIM + k0 + lc, &Bs[w * 32 + 16][0]);
        __syncthreads();
        bf16x8 a[4], b[4];
        #pragma unroll
        for (int i = 0; i < 4; ++i) a[i] = *(const bf16x8*)&As[wm + i * 16 + col][quad * 8];
        #pragma unroll
        for (int j = 0; j < 4; ++j) b[j] = *(const bf16x8*)&Bs[wn + j * 16 + col][quad * 8];
        #pragma unroll
        for (int i = 0; i < 4; ++i)
            #pragma unroll
            for (int j = 0; j < 4; ++j)
                acc[i][j] = MFMA(a[i], b[j], acc[i][j]);
        __syncthreads();
    }

    const int cgb = n0 + wn;                    // multiple of 64 -> fixed slot,h
    const int slot = cgb / DIM;
    const int h = (cgb % DIM) >> 6;
    const bool act = (slot < 2);
    const int sh = slot * 48 + (m0 >> 10) * NH + h;
    const int npb = (m0 & 1023) + wm + quad * 4;
    #pragma unroll
    for (int j = 0; j < 4; ++j) {
        unsigned short* dcol = T + ((size_t)(sh * HD + j * 16 + col)) * NP + npb;
        #pragma unroll
        for (int i = 0; i < 4; ++i) {
            alignas(8) unsigned short t4[4];
            #pragma unroll
            for (int r = 0; r < 4; ++r) {
                float v = acc[i][j][r];
                if (act) v = fmaxf(v, 0.f) + EPS;
                t4[r] = f2b(v);
            }
            *(uint2*)(dcol + i * 16) = *(const uint2*)t4;
        }
    }
}

// --------------------------------------------------------------------------
// graphmix (q and k fused, mask tile shared):
//   q2[which][bh][m][d] = f(m,d) + 0.1 * sum_n mask[n,m] f(n,d)
// band: n grid-rows [2mt-5, 2mt+6].
// --------------------------------------------------------------------------
__global__ __launch_bounds__(256) void k_graphmix(const unsigned short* __restrict__ maskT,
                                                  const unsigned short* __restrict__ T,
                                                  unsigned short* __restrict__ q2) {
    const int bh = blockIdx.y, mt = blockIdx.x;
    const int m0 = mt * 64, gr = 2 * mt;
    __shared__ unsigned short Ms[64][32], Fq[64][32], Fk[64][32];
    __shared__ unsigned short Sq[64][72], Sk[64][72];
    const int tid = threadIdx.x, w = tid >> 6, l = tid & 63;
    const int quad = l >> 4, col = l & 15;
    const int lr = l >> 2, lc = (l & 3) * 8;
    const unsigned short* Tq = T + (size_t)bh * HD * NP;
    const unsigned short* Tk = T + (size_t)(48 + bh) * HD * NP;

    f32x4 accq[4] = {}, acck[4] = {};
    const int r0 = max(0, gr - 5), r1 = min(31, gr + 6);
    for (int rw = r0; rw <= r1; ++rw) {
        const int nc = rw * 32;
        __syncthreads();
        gld16(maskT + (size_t)(m0 + w * 16 + lr) * NP + nc + lc, &Ms[w * 16][0]);
        gld16(Tq + (size_t)(w * 16 + lr) * NP + nc + lc, &Fq[w * 16][0]);
        gld16(Tk + (size_t)(w * 16 + lr) * NP + nc + lc, &Fk[w * 16][0]);
        __syncthreads();
        if (rw == gr || rw == gr + 1) {       // save f tiles covering our m-range
            const int off = (rw - gr) * 32;
            *(uint4*)&Sq[w * 16 + lr][off + lc] = *(const uint4*)&Fq[w * 16 + lr][lc];
            *(uint4*)&Sk[w * 16 + lr][off + lc] = *(const uint4*)&Fk[w * 16 + lr][lc];
        }
        bf16x8 a = *(const bf16x8*)&Ms[w * 16 + col][quad * 8];
        #pragma unroll
        for (int dt = 0; dt < 4; ++dt) {
            accq[dt] = MFMA(a, *(const bf16x8*)&Fq[dt * 16 + col][quad * 8], accq[dt]);
            acck[dt] = MFMA(a, *(const bf16x8*)&Fk[dt * 16 + col][quad * 8], acck[dt]);
        }
    }
    __syncthreads();
    unsigned short* q2q = q2 + ((size_t)bh * NP + m0) * HD;
    unsigned short* q2k = q2 + ((size_t)(48 + bh) * NP + m0) * HD;
    #pragma unroll
    for (int dt = 0; dt < 4; ++dt)
        #pragma unroll
        for (int r = 0; r < 4; ++r) {
            const int ml = w * 16 + quad * 4 + r;
            const int d = dt * 16 + col;
            q2q[(size_t)ml * HD + d] = f2b(b2f(Sq[d][ml]) + 0.1f * accq[dt][r]);
            q2k[(size_t)ml * HD + d] = f2b(b2f(Sk[d][ml]) + 0.1f * acck[dt][r]);
        }
}

// --------------------------------------------------------------------------
// attention: 128-row Q tiles; band m-tiles [2nt2-3, 2nt2+4]; half-K split
// LDS buffers (64B rows -> 2-way conflict-free b128 frag reads).
// --------------------------------------------------------------------------
__global__ __launch_bounds__(256) void k_attn(const unsigned short* __restrict__ q2,
                                              const unsigned short* __restrict__ T,
                                              const float* __restrict__ mask,
                                              unsigned short* __restrict__ attnb) {
    const int bh = blockIdx.y, b = bh / NH, h = bh % NH;
    const int nt2 = blockIdx.x, n0 = nt2 * 128;
    __shared__ unsigned short Qs[2][128][32];
    __shared__ unsigned short Ks[2][64][32];
    __shared__ unsigned short VT[2][64][32];
    __shared__ unsigned short Ss[128][72];
    __shared__ float rowz[128];
    const int tid = threadIdx.x, w = tid >> 6, l = tid & 63;
    const int quad = l >> 4, col = l & 15;
    const int lr = l >> 2, lc = (l & 3) * 8;

    const unsigned short* qb = q2 + ((size_t)bh * NP + n0) * HD;
    const unsigned short* kb = q2 + (size_t)(48 + bh) * NP * HD;
    const unsigned short* vtb = T + (size_t)(96 + bh) * HD * NP;

    #pragma unroll
    for (int hh = 0; hh < 2; ++hh)
        #pragma unroll
        for (int c = 0; c < 2; ++c)
            gld16(qb + (size_t)(w * 32 + c * 16 + lr) * HD + hh * 32 + lc,
                  &Qs[hh][w * 32 + c * 16][0]);

    f32x4 oacc[2][4] = {};
    float racc[2][4] = {};
    const int mlo = max(0, 2 * nt2 - 3), mhi = min(15, 2 * nt2 + 4);

    for (int mt = mlo; mt <= mhi; ++mt) {
        const int m0 = mt * 64;
        float mreg[2][4][4];               // prefetch mask into regs pre-barrier
        #pragma unroll
        for (int rg = 0; rg < 2; ++rg)
            #pragma unroll
            for (int mtt = 0; mtt < 4; ++mtt)
                #pragma unroll
                for (int r = 0; r < 4; ++r)
                    mreg[rg][mtt][r] = mask[(size_t)(n0 + (w * 2 + rg) * 16 + quad * 4 + r) * NP
                                            + m0 + mtt * 16 + col];
        __syncthreads();                   // prior iter's Ks/VT/Ss reads done
        #pragma unroll
        for (int hh = 0; hh < 2; ++hh) {
            gld16(kb + (size_t)(m0 + w * 16 + lr) * HD + hh * 32 + lc, &Ks[hh][w * 16][0]);
            gld16(vtb + (size_t)(w * 16 + lr) * NP + m0 + hh * 32 + lc, &VT[hh][w * 16][0]);
        }
        __syncthreads();

        f32x4 s[2][4] = {};
        #pragma unroll
        for (int ks = 0; ks < 2; ++ks) {
            bf16x8 bk[4];
            #pragma unroll
            for (int mtt = 0; mtt < 4; ++mtt) bk[mtt] = *(const bf16x8*)&Ks[ks][mtt * 16 + col][quad * 8];
            #pragma unroll
            for (int rg = 0; rg < 2; ++rg) {
                bf16x8 aq = *(const bf16x8*)&Qs[ks][(w * 2 + rg) * 16 + col][quad * 8];
                #pragma unroll
                for (int mtt = 0; mtt < 4; ++mtt) s[rg][mtt] = MFMA(aq, bk[mtt], s[rg][mtt]);
            }
        }
        #pragma unroll
        for (int rg = 0; rg < 2; ++rg)
            #pragma unroll
            for (int mtt = 0; mtt < 4; ++mtt)
                #pragma unroll
                for (int r = 0; r < 4; ++r) {
                    float v = s[rg][mtt][r] * mreg[rg][mtt][r];
                    racc[rg][r] += v;
                    Ss[(w * 2 + rg) * 16 + quad * 4 + r][mtt * 16 + col] = f2b(v);
                }
        __syncthreads();
        #pragma unroll
        for (int ks = 0; ks < 2; ++ks) {
            bf16x8 bv[4];
            #pragma unroll
            for (int dt = 0; dt < 4; ++dt) bv[dt] = *(const bf16x8*)&VT[ks][dt * 16 + col][quad * 8];
            #pragma unroll
            for (int rg = 0; rg < 2; ++rg) {
                bf16x8 as = *(const bf16x8*)&Ss[(w * 2 + rg) * 16 + col][ks * 32 + quad * 8];
                #pragma unroll
                for (int dt = 0; dt < 4; ++dt) oacc[rg][dt] = MFMA(as, bv[dt], oacc[rg][dt]);
            }
        }
    }

    #pragma unroll
    for (int rg = 0; rg < 2; ++rg)
        #pragma unroll
        for (int r = 0; r < 4; ++r) {
            float v = racc[rg][r];
            v += __shfl_xor(v, 1); v += __shfl_xor(v, 2);
            v += __shfl_xor(v, 4); v += __shfl_xor(v, 8);
            if (col == 0) rowz[(w * 2 + rg) * 16 + quad * 4 + r] = v;
        }
    __syncthreads();
    #pragma unroll
    for (int rg = 0; rg < 2; ++rg)
        #pragma unroll
        for (int r = 0; r < 4; ++r) {
            const int nl = (w * 2 + rg) * 16 + quad * 4 + r;
            const float z = 1.f / (rowz[nl] + EPS);
            #pragma unroll
            for (int dt = 0; dt < 4; ++dt)
                attnb[(size_t)(b * NP + n0 + nl) * DIM + h * HD + dt * 16 + col] =
                    f2b(oacc[rg][dt][r] * z);
        }
}

// --------------------------------------------------------------------------
// gemm2: out = attnb @ WoutT^T + b_out (fp32 out). 64x64 tiles -> grid
// 12x64 = 768 blocks (3.0 even rounds on 256 CUs; old 6x32=192 left 25% idle).
// --------------------------------------------------------------------------
__global__ __launch_bounds__(256) void k_gemm2(const unsigned short* __restrict__ A,
                                               const unsigned short* __restrict__ Bt,
                                               const float* __restrict__ bias,
                                               float* __restrict__ C) {
    __shared__ unsigned short As[64][32];
    __shared__ unsigned short Bs[64][32];
    const int tid = threadIdx.x, w = tid >> 6, l = tid & 63;
    const int m0 = blockIdx.y * 64, n0 = blockIdx.x * 64;
    const int wm = (w >> 1) * 32, wn = (w & 1) * 32;
    const int quad = l >> 4, col = l & 15;
    const int lr = l >> 2, lc = (l & 3) * 8;

    f32x4 acc[2][2] = {};
    for (int k0 = 0; k0 < DIM; k0 += 32) {
        gld16(A + (size_t)(m0 + w * 16 + lr) * DIM + k0 + lc, &As[w * 16][0]);
        gld16(Bt + (size_t)(n0 + w * 16 + lr) * DIM + k0 + lc, &Bs[w * 16][0]);
        __syncthreads();
        bf16x8 a[2], b[2];
        #pragma unroll
        for (int i = 0; i < 2; ++i) a[i] = *(const bf16x8*)&As[wm + i * 16 + col][quad * 8];
        #pragma unroll
        for (int j = 0; j < 2; ++j) b[j] = *(const bf16x8*)&Bs[wn + j * 16 + col][quad * 8];
        #pragma unroll
        for (int i = 0; i < 2; ++i)
            #pragma unroll
            for (int j = 0; j < 2; ++j)
                acc[i][j] = MFMA(a[i], b[j], acc[i][j]);
        __syncthreads();
    }
    #pragma unroll
    for (int i = 0; i < 2; ++i)
        #pragma unroll
        for (int j = 0; j < 2; ++j) {
            const int n = n0 + wn + j * 16 + col;
            #pragma unroll
            for (int r = 0; r < 4; ++r) {
                const int m = m0 + wm + i * 16 + quad * 4 + r;
                C[(size_t)m * DIM + n] = acc[i][j][r] + bias[n];
            }
        }
}

// --------------------------------------------------------------------------
extern "C" void kernel_launch(void* const* d_in, const int* in_sizes, int n_in,
                              void* d_out, int out_size, void* d_ws, size_t ws_size,
                              hipStream_t stream) {
    (void)in_sizes; (void)n_in; (void)out_size; (void)ws_size;
    const float* x     = (const float*)d_in[0];
    const float* W_qkv = (const float*)d_in[1];
    const float* W_out = (const float*)d_in[2];
    const float* b_out = (const float*)d_in[3];
    const float* mask  = (const float*)d_in[4];
    float* out = (float*)d_out;

    unsigned short* p = (unsigned short*)d_ws;
    unsigned short* xb    = p; p += (size_t)4096 * DIM;
    unsigned short* WqkvT = p; p += (size_t)TQ * DIM;
    unsigned short* WoutT = p; p += (size_t)DIM * DIM;
    unsigned short* maskT = p; p += (size_t)NP * NP;
    unsigned short* T     = p; p += (size_t)3 * 48 * HD * NP;
    unsigned short* q2    = p; p += (size_t)2 * 48 * NP * HD;
    unsigned short* attnb = p; p += (size_t)4096 * DIM;

    k_prep<<<dim3(2368), 256, 0, stream>>>(x, W_qkv, W_out, mask, xb, WqkvT, WoutT, maskT);
    k_gemm1<<<dim3(TQ / 128, 4096 / 128), 256, 0, stream>>>(xb, WqkvT, T);
    k_graphmix<<<dim3(NP / 64, 48), 256, 0, stream>>>(maskT, T, q2);
    k_attn<<<dim3(NP / 128, 48), 256, 0, stream>>>(q2, T, mask, attnb);
    k_gemm2<<<dim3(DIM / 64, 4096 / 64), 256, 0, stream>>>(attnb, WoutT, b_out, out);
}